// Round 21
// baseline (158.965 us; speedup 1.0000x reference)
//
#include <hip/hip_runtime.h>
#include <hip/hip_fp16.h>
#include <cstdint>
#include <cstddef>

#define BB 4
#define NN 1024
#define EMB_ 64
#define NH_ 8
#define BH_ (BB*NH_)
#define HID_ 256
#define K_ 8
#define NPTS_ 64
#define ROWS1 4
#define QB 1024  // qkv blocks (4096 rows / ROWS1)
#define CAP 256  // bucket capacity per (b,row)

typedef _Float16 v2h __attribute__((ext_vector_type(2)));

// ---------------- threefry2x32 (JAX-compatible, 20 rounds) ----------------
__host__ __device__ inline void tf2x32(uint32_t k0, uint32_t k1, uint32_t c0, uint32_t c1,
                                       uint32_t &o0, uint32_t &o1) {
  uint32_t ks2 = k0 ^ k1 ^ 0x1BD11BDAu;
  uint32_t x0 = c0 + k0, x1 = c1 + k1;
#define TFR(r) { x0 += x1; x1 = (x1 << (r)) | (x1 >> (32 - (r))); x1 ^= x0; }
  TFR(13) TFR(15) TFR(26) TFR(6)
  x0 += k1;  x1 += ks2 + 1u;
  TFR(17) TFR(29) TFR(16) TFR(24)
  x0 += ks2; x1 += k0 + 2u;
  TFR(13) TFR(15) TFR(26) TFR(6)
  x0 += k0;  x1 += k1 + 3u;
  TFR(17) TFR(29) TFR(16) TFR(24)
  x0 += k1;  x1 += ks2 + 4u;
  TFR(13) TFR(15) TFR(26) TFR(6)
  x0 += ks2; x1 += k0 + 5u;
#undef TFR
  o0 = x0; o1 = x1;
}

__device__ inline uint32_t tf_bits(uint32_t k0, uint32_t k1, uint32_t idx) {
  uint32_t a, b;
  tf2x32(k0, k1, 0u, idx, a, b);
  return a ^ b;
}

__device__ inline float softplusf(float v) {
  return fmaxf(v, 0.f) + log1pf(expf(-fabsf(v)));
}

// ---------------- K1: fused QKV projection + MLP/points + bucket write -----
// Journal: plain launch_bounds (R7: (256,4) -> spills). #pragma unroll 1
// (R6/R9: full unroll -> 256 VGPR). R16: single-pass QKV (x-tile read once).
// R17/R18: persistent attn REGRESSED 3-4x — do not persist. R20: q fp16.
// R21: depth-1 W prefetch — R15's version was neutral because LDS reads
// dominated then; R16 removed those, so W-load latency is now the exposed
// path (VALU 33%, FETCH 2.5 MB L2-resident). VGPR 48+12=60 < 64 quantum.
__global__ void __launch_bounds__(256) pre_kernel(
    const float* __restrict__ x,
    const float* __restrict__ Wq, const float* __restrict__ Wk, const float* __restrict__ Wv,
    const float* __restrict__ Wp1, const float* __restrict__ bp1,
    const float* __restrict__ Wp2, const float* __restrict__ bp2,
    const float* __restrict__ mvalues,
    __half* __restrict__ q, __half* __restrict__ k, __half* __restrict__ v,
    uint32_t* __restrict__ bucket, int* __restrict__ cursor,
    uint32_t kg0, uint32_t kg1, uint32_t kl0, uint32_t kl1) {
  __shared__ float xq[ROWS1][EMB_];
  __shared__ float xs[4][EMB_];
  __shared__ float hs[4][HID_];
  __shared__ float ps[4][16];
  __shared__ float meanv[4][K_], invsig[4][K_];
  __shared__ int flv[4][K_];
  __shared__ int pk[4][NPTS_];

  if (blockIdx.x < QB) {
    // ================= QKV: one pass over x-tile, 3 matrices =============
    const int block0 = blockIdx.x * ROWS1;
    const int t = threadIdx.x;
    xq[t >> 6][t & 63] = x[(size_t)block0 * EMB_ + t];   // 4x64 tile
    __syncthreads();
    const float qkscale = 0.3535533905932738f; // 64^-0.25

    for (int half = 0; half < 2; half++) {
      const int c = half * 256 + t;
      float aq[ROWS1], ak[ROWS1], av[ROWS1];
#pragma unroll
      for (int r = 0; r < ROWS1; r++) { aq[r] = 0.f; ak[r] = 0.f; av[r] = 0.f; }
      // prologue: load iter-0 W values
      float q0 = Wq[0 * 512 + c], q1 = Wq[1 * 512 + c];
      float q2 = Wq[2 * 512 + c], q3 = Wq[3 * 512 + c];
      float k0 = Wk[0 * 512 + c], k1 = Wk[1 * 512 + c];
      float k2 = Wk[2 * 512 + c], k3 = Wk[3 * 512 + c];
      float v0 = Wv[0 * 512 + c], v1 = Wv[1 * 512 + c];
      float v2 = Wv[2 * 512 + c], v3 = Wv[3 * 512 + c];
#pragma unroll 1
      for (int i4 = 0; i4 < EMB_; i4 += 4) {
        // issue next iteration's 12 W loads before this iteration's FMAs
        float nq0 = 0.f, nq1 = 0.f, nq2 = 0.f, nq3 = 0.f;
        float nk0 = 0.f, nk1 = 0.f, nk2 = 0.f, nk3 = 0.f;
        float nv0 = 0.f, nv1 = 0.f, nv2 = 0.f, nv3 = 0.f;
        if (i4 + 4 < EMB_) {
          nq0 = Wq[(i4 + 4) * 512 + c]; nq1 = Wq[(i4 + 5) * 512 + c];
          nq2 = Wq[(i4 + 6) * 512 + c]; nq3 = Wq[(i4 + 7) * 512 + c];
          nk0 = Wk[(i4 + 4) * 512 + c]; nk1 = Wk[(i4 + 5) * 512 + c];
          nk2 = Wk[(i4 + 6) * 512 + c]; nk3 = Wk[(i4 + 7) * 512 + c];
          nv0 = Wv[(i4 + 4) * 512 + c]; nv1 = Wv[(i4 + 5) * 512 + c];
          nv2 = Wv[(i4 + 6) * 512 + c]; nv3 = Wv[(i4 + 7) * 512 + c];
        }
#pragma unroll
        for (int r = 0; r < ROWS1; r++) {
          const float4 xv = *(const float4*)&xq[r][i4];   // ds_read_b128, read ONCE
          aq[r] += xv.x * q0 + xv.y * q1 + xv.z * q2 + xv.w * q3;
          ak[r] += xv.x * k0 + xv.y * k1 + xv.z * k2 + xv.w * k3;
          av[r] += xv.x * v0 + xv.y * v1 + xv.z * v2 + xv.w * v3;
        }
        q0 = nq0; q1 = nq1; q2 = nq2; q3 = nq3;
        k0 = nk0; k1 = nk1; k2 = nk2; k3 = nk3;
        v0 = nv0; v1 = nv1; v2 = nv2; v3 = nv3;
      }
      const int h = c >> 6, j = c & 63;
#pragma unroll
      for (int r = 0; r < ROWS1; r++) {
        const int gr = block0 + r;
        const int b = gr >> 10, n = gr & 1023;
        const size_t o = ((size_t)(b * NH_ + h) * NN + n) * EMB_ + j;
        q[o] = __float2half(aq[r] * qkscale);
        k[o] = __float2half(ak[r] * qkscale);
        v[o] = __float2half(av[r]);
      }
    }
    return;
  }

  // ================= points (4 bn per block; round-5 proven path) =========
  const int w = threadIdx.x >> 6, lane = threadIdx.x & 63;
  const int bn = (blockIdx.x - QB) * 4 + w;
  const int b = bn >> 10, n = bn & 1023;

  xs[w][lane] = x[(size_t)bn * EMB_ + lane];
  __syncthreads();

#pragma unroll
  for (int cc = 0; cc < 4; cc++) {
    const int c = cc * 64 + lane;
    float a = bp1[c];
    for (int i = 0; i < EMB_; i++) a += xs[w][i] * Wp1[i * HID_ + c];
    hs[w][c] = fmaxf(a, 0.f);
  }
  __syncthreads();

  if (lane < 16) {
    float a = bp2[lane];
    for (int c = 0; c < HID_; c++) a += hs[w][c] * Wp2[c * 16 + lane];
    ps[w][lane] = a;
  }
  __syncthreads();

  if (lane < K_) {
    const float rm = ps[w][lane], rs = ps[w][K_ + lane];
    float mean = (float)n - softplusf(rm);
    mean = fminf(fmaxf(mean, 0.f), (float)(NN - 1));
    const float sig = softplusf(rs + 2.0f) + 1e-6f;
    meanv[w][lane] = mean;
    invsig[w][lane] = 1.f / sig;
    flv[w][lane] = (int)floorf(mean);
  }
  __syncthreads();

  const int kk = lane >> 3, j = lane & 7;
  const int fl = flv[w][kk];
  int row, col;
  if (j < 4) {
    row = fl + (j >> 1);
    col = fl + (j & 1);
  } else if (j < 6) {
    const int g = j - 4;
    const uint32_t base = ((uint32_t)(bn * K_ + kk) * 2u + (uint32_t)g) * 2u;
    row = (int)(tf_bits(kg0, kg1, base + 0u) & 1023u);
    col = (int)(tf_bits(kg0, kg1, base + 1u) & 1023u);
  } else {
    const int a = j - 6;
    const uint32_t base = ((uint32_t)(bn * K_ + kk) * 2u + (uint32_t)a) * 2u;
    row = fl - 1 + (int)(tf_bits(kl0, kl1, base + 0u) & 1u);
    col = fl - 1 + (int)(tf_bits(kl0, kl1, base + 1u) & 1u);
  }
  row = min(max(row, 0), NN - 1);
  col = min(max(col, 0), NN - 1);
  const int packed = (row << 16) | col;
  pk[w][lane] = packed;
  __syncthreads();

  bool dup = false;
  for (int p2 = 0; p2 < lane; p2++)
    if (pk[w][p2] == packed) dup = true;

  const float frow = (float)row, fcol = (float)col;
  float dens[K_];
#pragma unroll
  for (int qd = 0; qd < K_; qd++) {
    const float dx = (frow - meanv[w][qd]) * invsig[w][qd];
    const float dy = (fcol - meanv[w][qd]) * invsig[w][qd];
    dens[qd] = dup ? 0.f : expf(-0.5f * (dx * dx + dy * dy));
  }
  float wsum = 0.f;
#pragma unroll
  for (int qd = 0; qd < K_; qd++) {
    float s = dens[qd];
    for (int d = 1; d < 64; d <<= 1) s += __shfl_xor(s, d);
    wsum += dens[qd] / s;
  }
  const float wgt = mvalues[n] * wsum;

  const int seg = b * NN + row;
  const uint32_t payload = ((uint32_t)col << 16) |
                           (uint32_t)__half_as_ushort(__float2half(wgt));
  const int pos = atomicAdd(&cursor[seg], 1);
  if (pos < CAP) bucket[((size_t)seg << 8) + pos] = payload;
}

// ---------------- K2: flash segment softmax + fused output projection ------
// R20 exact (83 us, fdot2 QK dot, q fp16). (512,6): R12 no-bound -> 68 VGPR;
// R13 (512,8) -> spills. R17/R18 persistence: FETCH x33 — never again.
__global__ void __launch_bounds__(512, 6) attn_out_kernel(
    const __half* __restrict__ q, const __half* __restrict__ k, const __half* __restrict__ v,
    const int* __restrict__ cursor, const uint32_t* __restrict__ bucket,
    const float* __restrict__ Wu, const float* __restrict__ bu,
    float* __restrict__ out) {
  __shared__ __half qs[NH_][EMB_];
  __shared__ float ps_lds[NH_][64];
  __shared__ int   cs_lds[NH_][64];
  __shared__ float ao[NH_][EMB_];
  __shared__ float op[NH_][EMB_];

  const int xcd = blockIdx.x & 7;
  const int rank = blockIdx.x >> 3;        // 0..511
  const int b = xcd >> 1;                  // 2 XCDs per batch
  const int row = (rank << 1) | (xcd & 1); // 0..1023

  const int h = threadIdx.x >> 6, lane = threadIdx.x & 63;
  const int bh = b * NH_ + h;

  const __half* __restrict__ kb = k + (size_t)bh * NN * EMB_;
  const __half* __restrict__ vb = v + (size_t)bh * NN * EMB_;
  const int seg = b * NN + row;
  const uint32_t* __restrict__ sp = bucket + ((size_t)seg << 8);

  qs[h][lane] = q[((size_t)bh * NN + row) * EMB_ + lane];
  const int len = min(cursor[seg], CAP);
  __syncthreads();

  float m = -INFINITY, Z = 0.f, acc = 0.f;

  for (int cb = 0; cb < len; cb += 64) {
    const int e = cb + lane;
    float logit = -INFINITY;
    int col = 0;
    if (e < len) {
      const uint32_t u = sp[e];
      col = (int)(u >> 16);
      const float wv = __half2float(__ushort_as_half((unsigned short)(u & 0xFFFFu)));
      const float4* __restrict__ kp4 = (const float4*)(kb + (size_t)col * EMB_);
      const float4* __restrict__ qp4 = (const float4*)qs[h];
      float dot = 0.f;
#pragma unroll
      for (int i = 0; i < 8; i++) {
        float4 kr = kp4[i];                 // 8 halves (global)
        float4 qr = qp4[i];                 // 8 halves (LDS)
        const v2h* ka = (const v2h*)&kr;
        const v2h* qa = (const v2h*)&qr;
#pragma unroll
        for (int jj = 0; jj < 4; jj++)
          dot = __builtin_amdgcn_fdot2(ka[jj], qa[jj], dot, false);
      }
      logit = wv * dot;
    }
    float cm = logit;
#pragma unroll
    for (int d = 1; d < 64; d <<= 1) cm = fmaxf(cm, __shfl_xor(cm, d));
    const float nm = fmaxf(m, cm);
    const float scale = expf(m - nm);            // 0 when m was -inf
    const float p = expf(logit - nm);            // 0 for e >= len
    float zs = p;
#pragma unroll
    for (int d = 1; d < 64; d <<= 1) zs += __shfl_xor(zs, d);
    Z = Z * scale + zs;
    m = nm;

    ps_lds[h][lane] = p;
    cs_lds[h][lane] = col;

    acc *= scale;
    const int lim = len - cb;
#pragma unroll
    for (int g = 0; g < 8; g++) {
      if (g * 8 < lim) {
#pragma unroll
        for (int u8 = 0; u8 < 8; u8++) {
          const int ee = g * 8 + u8;
          acc += ps_lds[h][ee] * __half2float(vb[(size_t)cs_lds[h][ee] * EMB_ + lane]);
        }
      }
    }
  }

  ao[h][lane] = (len > 0) ? acc / Z : 0.f;
  __syncthreads();

  float s = 0.f;
  const float* __restrict__ wu_h = Wu + (size_t)(h * 64) * EMB_;
#pragma unroll
  for (int d = 0; d < 64; d++)
    s += ao[h][d] * wu_h[d * EMB_ + lane];
  op[h][lane] = s;
  __syncthreads();

  if (h == 0) {
    float t = bu[lane];
#pragma unroll
    for (int hh = 0; hh < NH_; hh++) t += op[hh][lane];
    out[(size_t)(b * NN + row) * EMB_ + lane] = t;
  }
}

// ---------------- host ----------------
extern "C" void kernel_launch(void* const* d_in, const int* in_sizes, int n_in,
                              void* d_out, int out_size, void* d_ws, size_t ws_size,
                              hipStream_t stream) {
  const float* x   = (const float*)d_in[0];
  const float* Wq  = (const float*)d_in[1];
  const float* Wk  = (const float*)d_in[2];
  const float* Wv  = (const float*)d_in[3];
  const float* Wu  = (const float*)d_in[4];
  const float* bu  = (const float*)d_in[5];
  const float* Wp1 = (const float*)d_in[6];
  const float* bp1 = (const float*)d_in[7];
  const float* Wp2 = (const float*)d_in[8];
  const float* bp2 = (const float*)d_in[9];
  const float* mv  = (const float*)d_in[10];
  float* out = (float*)d_out;

  char* ws = (char*)d_ws;
  size_t off = 0;
  auto alloc = [&](size_t bytes) -> void* {
    void* p = ws + off;
    off += (bytes + 255) & ~(size_t)255;
    return p;
  };
  const size_t QH = (size_t)BH_ * NN * EMB_ * sizeof(__half);  // 4 MB
  __half*   q      = (__half*)  alloc(QH);
  __half*   k      = (__half*)  alloc(QH);
  __half*   v      = (__half*)  alloc(QH);
  uint32_t* bucket = (uint32_t*)alloc((size_t)BB * NN * CAP * sizeof(uint32_t)); // 4 MB
  int*      cursor = (int*)     alloc((size_t)BB * NN * sizeof(int));
  if (off > ws_size) return;

  uint32_t kgA, kgB, klA, klB;
  tf2x32(0u, 42u, 0u, 0u, kgA, kgB);  // kg
  tf2x32(0u, 42u, 0u, 1u, klA, klB);  // kl
  uint32_t kg2A, kg2B, kl2A, kl2B;
  tf2x32(kgA, kgB, 0u, 1u, kg2A, kg2B); // split(kg)[1]
  tf2x32(klA, klB, 0u, 1u, kl2A, kl2B); // split(kl)[1]

  hipMemsetAsync(cursor, 0, (size_t)BB * NN * sizeof(int), stream);

  pre_kernel<<<QB + (BB * NN) / 4, 256, 0, stream>>>(
      x, Wq, Wk, Wv, Wp1, bp1, Wp2, bp2, mv, q, k, v, bucket, cursor,
      kg2A, kg2B, kl2A, kl2B);
  attn_out_kernel<<<BB * NN, 512, 0, stream>>>(q, k, v, cursor, bucket,
                                               Wu, bu, out);
}

// Round 22
// 155.462 us; speedup vs baseline: 1.0225x; 1.0225x over previous
//
#include <hip/hip_runtime.h>
#include <hip/hip_fp16.h>
#include <cstdint>
#include <cstddef>

#define BB 4
#define NN 1024
#define EMB_ 64
#define NH_ 8
#define BH_ (BB*NH_)
#define HID_ 256
#define K_ 8
#define NPTS_ 64
#define ROWS1 4
#define QB 1024  // qkv blocks (4096 rows / ROWS1)
#define CAP 256  // bucket capacity per (b,row)

typedef _Float16 v2h __attribute__((ext_vector_type(2)));

// ---------------- threefry2x32 (JAX-compatible, 20 rounds) ----------------
__host__ __device__ inline void tf2x32(uint32_t k0, uint32_t k1, uint32_t c0, uint32_t c1,
                                       uint32_t &o0, uint32_t &o1) {
  uint32_t ks2 = k0 ^ k1 ^ 0x1BD11BDAu;
  uint32_t x0 = c0 + k0, x1 = c1 + k1;
#define TFR(r) { x0 += x1; x1 = (x1 << (r)) | (x1 >> (32 - (r))); x1 ^= x0; }
  TFR(13) TFR(15) TFR(26) TFR(6)
  x0 += k1;  x1 += ks2 + 1u;
  TFR(17) TFR(29) TFR(16) TFR(24)
  x0 += ks2; x1 += k0 + 2u;
  TFR(13) TFR(15) TFR(26) TFR(6)
  x0 += k0;  x1 += k1 + 3u;
  TFR(17) TFR(29) TFR(16) TFR(24)
  x0 += k1;  x1 += ks2 + 4u;
  TFR(13) TFR(15) TFR(26) TFR(6)
  x0 += ks2; x1 += k0 + 5u;
#undef TFR
  o0 = x0; o1 = x1;
}

__device__ inline uint32_t tf_bits(uint32_t k0, uint32_t k1, uint32_t idx) {
  uint32_t a, b;
  tf2x32(k0, k1, 0u, idx, a, b);
  return a ^ b;
}

__device__ inline float softplusf(float v) {
  return fmaxf(v, 0.f) + log1pf(expf(-fabsf(v)));
}

// ---------------- K1: fused QKV projection + MLP/points + bucket write -----
// Journal: plain launch_bounds (R7: (256,4) -> spills). #pragma unroll 1
// (R6/R9: full unroll -> 256 VGPR). R16: single-pass QKV (x-tile read once).
// R17/R18: persistent attn REGRESSED 3-4x — do not persist. R20: q fp16.
// R15/R21: manual W prefetch neutral twice (compiler re-sinks it) — removed.
__global__ void __launch_bounds__(256) pre_kernel(
    const float* __restrict__ x,
    const float* __restrict__ Wq, const float* __restrict__ Wk, const float* __restrict__ Wv,
    const float* __restrict__ Wp1, const float* __restrict__ bp1,
    const float* __restrict__ Wp2, const float* __restrict__ bp2,
    const float* __restrict__ mvalues,
    __half* __restrict__ q, __half* __restrict__ k, __half* __restrict__ v,
    uint32_t* __restrict__ bucket, int* __restrict__ cursor,
    uint32_t kg0, uint32_t kg1, uint32_t kl0, uint32_t kl1) {
  __shared__ float xq[ROWS1][EMB_];
  __shared__ float xs[4][EMB_];
  __shared__ float hs[4][HID_];
  __shared__ float ps[4][16];
  __shared__ float meanv[4][K_], invsig[4][K_];
  __shared__ int flv[4][K_];
  __shared__ int pk[4][NPTS_];

  if (blockIdx.x < QB) {
    // ================= QKV: one pass over x-tile, 3 matrices =============
    const int block0 = blockIdx.x * ROWS1;
    const int t = threadIdx.x;
    xq[t >> 6][t & 63] = x[(size_t)block0 * EMB_ + t];   // 4x64 tile
    __syncthreads();
    const float qkscale = 0.3535533905932738f; // 64^-0.25

    for (int half = 0; half < 2; half++) {
      const int c = half * 256 + t;
      float aq[ROWS1], ak[ROWS1], av[ROWS1];
#pragma unroll
      for (int r = 0; r < ROWS1; r++) { aq[r] = 0.f; ak[r] = 0.f; av[r] = 0.f; }
#pragma unroll 1
      for (int i4 = 0; i4 < EMB_; i4 += 4) {
        const float q0 = Wq[(i4 + 0) * 512 + c];
        const float q1 = Wq[(i4 + 1) * 512 + c];
        const float q2 = Wq[(i4 + 2) * 512 + c];
        const float q3 = Wq[(i4 + 3) * 512 + c];
        const float k0 = Wk[(i4 + 0) * 512 + c];
        const float k1 = Wk[(i4 + 1) * 512 + c];
        const float k2 = Wk[(i4 + 2) * 512 + c];
        const float k3 = Wk[(i4 + 3) * 512 + c];
        const float v0 = Wv[(i4 + 0) * 512 + c];
        const float v1 = Wv[(i4 + 1) * 512 + c];
        const float v2 = Wv[(i4 + 2) * 512 + c];
        const float v3 = Wv[(i4 + 3) * 512 + c];
#pragma unroll
        for (int r = 0; r < ROWS1; r++) {
          const float4 xv = *(const float4*)&xq[r][i4];   // ds_read_b128, read ONCE
          aq[r] += xv.x * q0 + xv.y * q1 + xv.z * q2 + xv.w * q3;
          ak[r] += xv.x * k0 + xv.y * k1 + xv.z * k2 + xv.w * k3;
          av[r] += xv.x * v0 + xv.y * v1 + xv.z * v2 + xv.w * v3;
        }
      }
      const int h = c >> 6, j = c & 63;
#pragma unroll
      for (int r = 0; r < ROWS1; r++) {
        const int gr = block0 + r;
        const int b = gr >> 10, n = gr & 1023;
        const size_t o = ((size_t)(b * NH_ + h) * NN + n) * EMB_ + j;
        q[o] = __float2half(aq[r] * qkscale);
        k[o] = __float2half(ak[r] * qkscale);
        v[o] = __float2half(av[r]);
      }
    }
    return;
  }

  // ================= points (4 bn per block; round-5 proven path) =========
  const int w = threadIdx.x >> 6, lane = threadIdx.x & 63;
  const int bn = (blockIdx.x - QB) * 4 + w;
  const int b = bn >> 10, n = bn & 1023;

  xs[w][lane] = x[(size_t)bn * EMB_ + lane];
  __syncthreads();

#pragma unroll
  for (int cc = 0; cc < 4; cc++) {
    const int c = cc * 64 + lane;
    float a = bp1[c];
    for (int i = 0; i < EMB_; i++) a += xs[w][i] * Wp1[i * HID_ + c];
    hs[w][c] = fmaxf(a, 0.f);
  }
  __syncthreads();

  if (lane < 16) {
    float a = bp2[lane];
    for (int c = 0; c < HID_; c++) a += hs[w][c] * Wp2[c * 16 + lane];
    ps[w][lane] = a;
  }
  __syncthreads();

  if (lane < K_) {
    const float rm = ps[w][lane], rs = ps[w][K_ + lane];
    float mean = (float)n - softplusf(rm);
    mean = fminf(fmaxf(mean, 0.f), (float)(NN - 1));
    const float sig = softplusf(rs + 2.0f) + 1e-6f;
    meanv[w][lane] = mean;
    invsig[w][lane] = 1.f / sig;
    flv[w][lane] = (int)floorf(mean);
  }
  __syncthreads();

  const int kk = lane >> 3, j = lane & 7;
  const int fl = flv[w][kk];
  int row, col;
  if (j < 4) {
    row = fl + (j >> 1);
    col = fl + (j & 1);
  } else if (j < 6) {
    const int g = j - 4;
    const uint32_t base = ((uint32_t)(bn * K_ + kk) * 2u + (uint32_t)g) * 2u;
    row = (int)(tf_bits(kg0, kg1, base + 0u) & 1023u);
    col = (int)(tf_bits(kg0, kg1, base + 1u) & 1023u);
  } else {
    const int a = j - 6;
    const uint32_t base = ((uint32_t)(bn * K_ + kk) * 2u + (uint32_t)a) * 2u;
    row = fl - 1 + (int)(tf_bits(kl0, kl1, base + 0u) & 1u);
    col = fl - 1 + (int)(tf_bits(kl0, kl1, base + 1u) & 1u);
  }
  row = min(max(row, 0), NN - 1);
  col = min(max(col, 0), NN - 1);
  const int packed = (row << 16) | col;
  pk[w][lane] = packed;
  __syncthreads();

  bool dup = false;
  for (int p2 = 0; p2 < lane; p2++)
    if (pk[w][p2] == packed) dup = true;

  const float frow = (float)row, fcol = (float)col;
  float dens[K_];
#pragma unroll
  for (int qd = 0; qd < K_; qd++) {
    const float dx = (frow - meanv[w][qd]) * invsig[w][qd];
    const float dy = (fcol - meanv[w][qd]) * invsig[w][qd];
    dens[qd] = dup ? 0.f : expf(-0.5f * (dx * dx + dy * dy));
  }
  float wsum = 0.f;
#pragma unroll
  for (int qd = 0; qd < K_; qd++) {
    float s = dens[qd];
    for (int d = 1; d < 64; d <<= 1) s += __shfl_xor(s, d);
    wsum += dens[qd] / s;
  }
  const float wgt = mvalues[n] * wsum;

  const int seg = b * NN + row;
  const uint32_t payload = ((uint32_t)col << 16) |
                           (uint32_t)__half_as_ushort(__float2half(wgt));
  const int pos = atomicAdd(&cursor[seg], 1);
  if (pos < CAP) bucket[((size_t)seg << 8) + pos] = payload;
}

// ---------------- K2: flash segment softmax + fused output projection ------
// R22: 256-thread blocks (4 heads), 8192 blocks -> 8 blocks/CU (vs 4) for
// finer scheduling + more in-flight gathers. Wu projection split: each
// half-block atomicAdds its 4-head partial into out (zeroed per call —
// harness does NOT re-poison between replays). Consecutive blocks share a
// row's bucket. (256,8) caps VGPR at 64, above ~40 demand (R13 lesson).
// R17/R18 persistence: FETCH x33 — never again.
__global__ void __launch_bounds__(256, 8) attn_out_kernel(
    const __half* __restrict__ q, const __half* __restrict__ k, const __half* __restrict__ v,
    const int* __restrict__ cursor, const uint32_t* __restrict__ bucket,
    const float* __restrict__ Wu, const float* __restrict__ bu,
    float* __restrict__ out) {
  __shared__ __half qs[4][EMB_];
  __shared__ float ps_lds[4][64];
  __shared__ int   cs_lds[4][64];
  __shared__ float ao[4][EMB_];
  __shared__ float op[4][EMB_];

  const int xcd = blockIdx.x & 7;
  const int rid = blockIdx.x >> 3;          // 0..1023
  const int b = xcd >> 1;                   // 2 XCDs per batch
  const int row = ((rid >> 1) << 1) | (xcd & 1);  // 0..1023
  const int half = rid & 1;                 // head group 0..3 / 4..7

  const int hl = threadIdx.x >> 6, lane = threadIdx.x & 63;
  const int head = half * 4 + hl;
  const int bh = b * NH_ + head;

  const __half* __restrict__ kb = k + (size_t)bh * NN * EMB_;
  const __half* __restrict__ vb = v + (size_t)bh * NN * EMB_;
  const int seg = b * NN + row;
  const uint32_t* __restrict__ sp = bucket + ((size_t)seg << 8);

  qs[hl][lane] = q[((size_t)bh * NN + row) * EMB_ + lane];
  const int len = min(cursor[seg], CAP);
  __syncthreads();

  float m = -INFINITY, Z = 0.f, acc = 0.f;

  for (int cb = 0; cb < len; cb += 64) {
    const int e = cb + lane;
    float logit = -INFINITY;
    int col = 0;
    if (e < len) {
      const uint32_t u = sp[e];
      col = (int)(u >> 16);
      const float wv = __half2float(__ushort_as_half((unsigned short)(u & 0xFFFFu)));
      const float4* __restrict__ kp4 = (const float4*)(kb + (size_t)col * EMB_);
      const float4* __restrict__ qp4 = (const float4*)qs[hl];
      float dot = 0.f;
#pragma unroll
      for (int i = 0; i < 8; i++) {
        float4 kr = kp4[i];                 // 8 halves (global)
        float4 qr = qp4[i];                 // 8 halves (LDS)
        const v2h* ka = (const v2h*)&kr;
        const v2h* qa = (const v2h*)&qr;
#pragma unroll
        for (int jj = 0; jj < 4; jj++)
          dot = __builtin_amdgcn_fdot2(ka[jj], qa[jj], dot, false);
      }
      logit = wv * dot;
    }
    float cm = logit;
#pragma unroll
    for (int d = 1; d < 64; d <<= 1) cm = fmaxf(cm, __shfl_xor(cm, d));
    const float nm = fmaxf(m, cm);
    const float scale = expf(m - nm);            // 0 when m was -inf
    const float p = expf(logit - nm);            // 0 for e >= len
    float zs = p;
#pragma unroll
    for (int d = 1; d < 64; d <<= 1) zs += __shfl_xor(zs, d);
    Z = Z * scale + zs;
    m = nm;

    ps_lds[hl][lane] = p;
    cs_lds[hl][lane] = col;

    acc *= scale;
    const int lim = len - cb;
#pragma unroll
    for (int g = 0; g < 8; g++) {
      if (g * 8 < lim) {
#pragma unroll
        for (int u8 = 0; u8 < 8; u8++) {
          const int ee = g * 8 + u8;
          acc += ps_lds[hl][ee] * __half2float(vb[(size_t)cs_lds[hl][ee] * EMB_ + lane]);
        }
      }
    }
  }

  ao[hl][lane] = (len > 0) ? acc / Z : 0.f;
  __syncthreads();

  float s = 0.f;
  const float* __restrict__ wu_h = Wu + (size_t)(head * 64) * EMB_;
#pragma unroll
  for (int d = 0; d < 64; d++)
    s += ao[hl][d] * wu_h[d * EMB_ + lane];
  op[hl][lane] = s;
  __syncthreads();

  if (hl == 0) {
    float t = (half == 0) ? bu[lane] : 0.f;
#pragma unroll
    for (int hh = 0; hh < 4; hh++) t += op[hh][lane];
    atomicAdd(&out[(size_t)(b * NN + row) * EMB_ + lane], t);
  }
}

// ---------------- host ----------------
extern "C" void kernel_launch(void* const* d_in, const int* in_sizes, int n_in,
                              void* d_out, int out_size, void* d_ws, size_t ws_size,
                              hipStream_t stream) {
  const float* x   = (const float*)d_in[0];
  const float* Wq  = (const float*)d_in[1];
  const float* Wk  = (const float*)d_in[2];
  const float* Wv  = (const float*)d_in[3];
  const float* Wu  = (const float*)d_in[4];
  const float* bu  = (const float*)d_in[5];
  const float* Wp1 = (const float*)d_in[6];
  const float* bp1 = (const float*)d_in[7];
  const float* Wp2 = (const float*)d_in[8];
  const float* bp2 = (const float*)d_in[9];
  const float* mv  = (const float*)d_in[10];
  float* out = (float*)d_out;

  char* ws = (char*)d_ws;
  size_t off = 0;
  auto alloc = [&](size_t bytes) -> void* {
    void* p = ws + off;
    off += (bytes + 255) & ~(size_t)255;
    return p;
  };
  const size_t QH = (size_t)BH_ * NN * EMB_ * sizeof(__half);  // 4 MB
  __half*   q      = (__half*)  alloc(QH);
  __half*   k      = (__half*)  alloc(QH);
  __half*   v      = (__half*)  alloc(QH);
  uint32_t* bucket = (uint32_t*)alloc((size_t)BB * NN * CAP * sizeof(uint32_t)); // 4 MB
  int*      cursor = (int*)     alloc((size_t)BB * NN * sizeof(int));
  if (off > ws_size) return;

  uint32_t kgA, kgB, klA, klB;
  tf2x32(0u, 42u, 0u, 0u, kgA, kgB);  // kg
  tf2x32(0u, 42u, 0u, 1u, klA, klB);  // kl
  uint32_t kg2A, kg2B, kl2A, kl2B;
  tf2x32(kgA, kgB, 0u, 1u, kg2A, kg2B); // split(kg)[1]
  tf2x32(klA, klB, 0u, 1u, kl2A, kl2B); // split(kl)[1]

  hipMemsetAsync(cursor, 0, (size_t)BB * NN * sizeof(int), stream);
  hipMemsetAsync(out, 0, (size_t)out_size * sizeof(float), stream); // attn atomicAdds

  pre_kernel<<<QB + (BB * NN) / 4, 256, 0, stream>>>(
      x, Wq, Wk, Wv, Wp1, bp1, Wp2, bp2, mv, q, k, v, bucket, cursor,
      kg2A, kg2B, kl2A, kl2B);
  attn_out_kernel<<<BB * NN * 2, 256, 0, stream>>>(q, k, v, cursor, bucket,
                                                   Wu, bu, out);
}